// Round 1
// baseline (43.113 us; speedup 1.0000x reference)
//
#include <hip/hip_runtime.h>

#define NB 32
#define NP 32
#define NS 512
#define NPS (NP * NS)   // 16384

// ---------------------------------------------------------------------------
// Kernel 1: pointRef[b, j] = quat_rotate(qn[b, j/S], (2*coef-1)*shape) + trans
// Stored padded to float4 in d_ws for aligned vector loads in kernel 2.
// ---------------------------------------------------------------------------
__global__ void points_kernel(const float* __restrict__ shape,   // (B,P,3)
                              const float* __restrict__ trans,   // (B,P,3)
                              const float* __restrict__ quat,    // (B,P,4)
                              const float* __restrict__ coef,    // (B,P,S,3)
                              float4* __restrict__ pts)          // (B*PS)
{
    int idx = blockIdx.x * blockDim.x + threadIdx.x;
    if (idx >= NB * NPS) return;
    int b = idx >> 14;              // / NPS
    int j = idx & (NPS - 1);
    int p = j >> 9;                 // / NS

    const float* q = quat + (size_t)(b * NP + p) * 4;
    float qw = q[0], qx = q[1], qy = q[2], qz = q[3];
    float inv = 1.0f / sqrtf(qw * qw + qx * qx + qy * qy + qz * qz);
    qw *= inv; qx *= inv; qy *= inv; qz *= inv;

    const float* sh = shape + (size_t)(b * NP + p) * 3;
    const float* tr = trans + (size_t)(b * NP + p) * 3;
    const float* c  = coef  + (size_t)idx * 3;

    float vx = (2.0f * c[0] - 1.0f) * sh[0];
    float vy = (2.0f * c[1] - 1.0f) * sh[1];
    float vz = (2.0f * c[2] - 1.0f) * sh[2];

    // uv = qv x v
    float ux = qy * vz - qz * vy;
    float uy = qz * vx - qx * vz;
    float uz = qx * vy - qy * vx;
    // uuv = qv x uv
    float uux = qy * uz - qz * uy;
    float uuy = qz * ux - qx * uz;
    float uuz = qx * uy - qy * ux;

    float px = vx + 2.0f * (qw * ux + uux) + tr[0];
    float py = vy + 2.0f * (qw * uy + uuy) + tr[1];
    float pz = vz + 2.0f * (qw * uz + uuz) + tr[2];

    pts[idx] = make_float4(px, py, pz, 0.0f);
}

// ---------------------------------------------------------------------------
// Kernel 2: for each (b, p, j): tsdfOut, weight, tsdfGT(=0).
// 256 threads/block, 4 j per thread -> 1024 j per block; 16 chunks per (b,p).
// grid = B*P*16 = 16384 blocks. Three coalesced float4 output streams.
// ---------------------------------------------------------------------------
__global__ void __launch_bounds__(256)
tsdf_kernel(const float* __restrict__ shape,   // (B,P,3)
            const float* __restrict__ trans,   // (B,P,3)
            const float* __restrict__ quat,    // (B,P,4)
            const float* __restrict__ iou,     // (B,P)
            const float4* __restrict__ pts,    // (B*PS)
            float* __restrict__ out)           // tsdfOut | weight | tsdfGT
{
    const size_t TOT = (size_t)NB * NP * NPS;

    int blk   = blockIdx.x;
    int chunk = blk & 15;          // 16 chunks of 1024
    int bp    = blk >> 4;
    int b     = bp >> 5;
    int p     = bp & 31;
    int j0    = chunk * 1024 + threadIdx.x * 4;

    // per-(b,p) scalars (broadcast loads)
    const float* q = quat + (size_t)bp * 4;
    float qw = q[0], qx = q[1], qy = q[2], qz = q[3];
    float inv = 1.0f / sqrtf(qw * qw + qx * qx + qy * qy + qz * qz);
    // conjugate quaternion qc = (w, -x, -y, -z), normalized
    qw *= inv; qx *= -inv; qy *= -inv; qz *= -inv;

    const float* sh = shape + (size_t)bp * 3;
    float sx = sh[0], sy = sh[1], sz = sh[2];
    const float* tr = trans + (size_t)bp * 3;
    float tx = tr[0], ty = tr[1], tz = tr[2];
    float iou_p = iou[bp];

    // weight value: vol[b, owner] where owner = j0/S (constant over the 4 j's)
    int owner = j0 >> 9;
    const float* sho = shape + (size_t)(b * NP + owner) * 3;
    float wval = sho[0] * sho[1] * sho[2] * iou[b * NP + owner];
    float mask = (owner != p) ? 1.0f : 0.0f;
    float scale = iou_p * mask;

    const float4* pbase = pts + (size_t)b * NPS + j0;

    float4 res;
    float* resv = &res.x;
    #pragma unroll
    for (int k = 0; k < 4; ++k) {
        float4 pt = pbase[k];
        float vx = pt.x - tx;
        float vy = pt.y - ty;
        float vz = pt.z - tz;
        // quat_rotate(qc, v)
        float ux = qy * vz - qz * vy;
        float uy = qz * vx - qx * vz;
        float uz = qx * vy - qy * vx;
        float uux = qy * uz - qz * uy;
        float uuy = qz * ux - qx * uz;
        float uuz = qx * uy - qy * ux;
        float lx = vx + 2.0f * (qw * ux + uux);
        float ly = vy + 2.0f * (qw * uy + uuy);
        float lz = vz + 2.0f * (qw * uz + uuz);
        float px_ = fmaxf(sx - fabsf(lx), 0.0f);
        float py_ = fmaxf(sy - fabsf(ly), 0.0f);
        float pz_ = fmaxf(sz - fabsf(lz), 0.0f);
        float tsdf = px_ * px_ + py_ * py_ + pz_ * pz_;
        resv[k] = tsdf * scale;
    }

    size_t base = (size_t)bp * NPS + j0;
    *(float4*)(out + base)            = res;
    *(float4*)(out + TOT + base)      = make_float4(wval, wval, wval, wval);
    *(float4*)(out + 2 * TOT + base)  = make_float4(0.0f, 0.0f, 0.0f, 0.0f);
}

extern "C" void kernel_launch(void* const* d_in, const int* in_sizes, int n_in,
                              void* d_out, int out_size, void* d_ws, size_t ws_size,
                              hipStream_t stream) {
    const float* shape = (const float*)d_in[0];   // (B,P,3)
    const float* trans = (const float*)d_in[1];   // (B,P,3)
    const float* quat  = (const float*)d_in[2];   // (B,P,4)
    const float* iou   = (const float*)d_in[3];   // (B,P)
    const float* coef  = (const float*)d_in[4];   // (B,P,S,3)
    float* out = (float*)d_out;
    float4* pts = (float4*)d_ws;                  // B*PS float4 = 8 MB

    int npts = NB * NPS;
    points_kernel<<<(npts + 255) / 256, 256, 0, stream>>>(shape, trans, quat, coef, pts);

    int nblocks = NB * NP * 16;                   // 16384
    tsdf_kernel<<<nblocks, 256, 0, stream>>>(shape, trans, quat, iou, pts, out);
}